// Round 5
// baseline (301.884 us; speedup 1.0000x reference)
//
#include <hip/hip_runtime.h>
#include <hip/hip_bf16.h>
#include <cstdint>
#include <cstddef>

// LSTM cell fused as one bf16 GEMM (m201-style 256^2 8-phase schedule) + in-register epilogue.
// A = [x|h] bf16 [8192][2048]. W = [Wx|Wh] bf16 [4096][2048], rows permuted
// n' = (o/16)*64 + g*16 + (o%16)  => a 64-col wave slice = 4 gates x same 16 output cols.
// GEMM: BM=BN=256, BK=64, 512 thr (8 waves 2Mx4N), per-wave 128x64, acc[8][4] f32x4.
// R4/R5 change vs R3: de-fenced. R3 had ~6 sched_barrier(0) + manual lgkmcnt(0) per phase
// (m141 pathology: order-pinning defeats compiler scheduling; MfmaUtil stuck at 38%).
// Now: single asm s_barrier with "memory" clobber per barrier point. The clobber keeps
// LDS write-after-read safety (gld_lds / ds_read are memory ops, cannot cross); the
// compiler's fine-grained lgkmcnt(4/3/1/0) before MFMAs returns (m97 r109 behavior),
// and loop-invariant ds-address VALU can be hoisted/cached.
// (R5 = byte-identical resubmit of R4; R4 died to a container-level infra failure with
// no measurement. Audit found no hang/fault path: uniform barrier counts, guarded OOB,
// vmcnt ledger exact, write-after-read separation >= 2 barriers.)
// Schedule per K-tile t (4 phases):
//   Ph1: ds_read A(mf0-3,k0)+B(all,k0);  stage B-HI of t+1 -> other buf
//   Ph2: ds_read A(mf0-3,k1)+B(all,k1);  stage A-HI of t+1 -> other buf
//   Ph3: ds_read A(mf4-7,k0);            stage A-LO of t+2 -> cur buf (freed after Ph2)
//   Ph4: ds_read A(mf4-7,k1);            stage B-LO of t+2 -> cur buf (freed after Ph2)
//   tile end: s_waitcnt vmcnt(4) when g2 (t+2 prefetch issued), else vmcnt(0) (tail).
//   Steady state ledger (load units, oldest first): AL(t+1)x2 BL(t+1)x2 | BH(t+1)x2
//   AH(t+1)x2 | AL(t+2)x2 BL(t+2)x2 = 12 outstanding; vmcnt(4) retires first 8 =
//   exactly tile t+1's data. Each phase: reads+stages, barrier, setprio1, 16 MFMA,
//   setprio0, barrier.

#define B_DIM   8192
#define IN_DIM  1024
#define H_DIM   1024
#define KTOT    2048
#define KROW    4096          // bytes per packed row
#define NT      32            // K-tiles of 64

typedef __attribute__((ext_vector_type(8))) short  bf16x8;
typedef __attribute__((ext_vector_type(4))) float  f32x4;

static __device__ __forceinline__ void gld_lds16(const void* g, void* l) {
    __builtin_amdgcn_global_load_lds(
        (const __attribute__((address_space(1))) void*)g,
        (__attribute__((address_space(3))) void*)l, 16, 0, 0);
}

static __device__ __forceinline__ unsigned short f2bf(float f) {
    union { float f; unsigned u; } v; v.f = f;
    unsigned r = v.u + 0x7fffu + ((v.u >> 16) & 1u);   // RNE
    return (unsigned short)(r >> 16);
}

// ---- fused pack: [x|h] -> Acat ; [Wx|Wh] -> Wcat (permuted rows) ----
__global__ __launch_bounds__(256) void pack_all(const float* __restrict__ x,
                                                const float* __restrict__ h,
                                                const float* __restrict__ Wx,
                                                const float* __restrict__ Wh,
                                                unsigned short* __restrict__ Acat,
                                                unsigned short* __restrict__ Wcat) {
    const int bid = blockIdx.x;
    const float* src;
    unsigned short* dst;
    int idx;
    if (bid < 8192) {                       // A part: 8192*2048/8 chunks
        idx = bid * 256 + threadIdx.x;
        int row = idx >> 8;
        int k0  = (idx & 255) * 8;
        src = (k0 < IN_DIM) ? (x + (size_t)row * IN_DIM + k0)
                            : (h + (size_t)row * H_DIM + (k0 - IN_DIM));
        dst = Acat + (size_t)idx * 8;
    } else {                                // W part: 4096*2048/8 chunks
        idx = (bid - 8192) * 256 + threadIdx.x;
        int n  = idx >> 8;                  // permuted row n'
        int k0 = (idx & 255) * 8;
        int ob64 = n >> 6, g = (n >> 4) & 3, ol = n & 15;
        int o = ob64 * 16 + ol;
        src = (k0 < IN_DIM)
            ? (Wx + (size_t)(g * H_DIM + o) * IN_DIM + k0)
            : (Wh + (size_t)(g * H_DIM + o) * H_DIM + (k0 - IN_DIM));
        dst = Wcat + (size_t)idx * 8;
    }
    f32x4 v0 = *(const f32x4*)src;
    f32x4 v1 = *(const f32x4*)(src + 4);
    unsigned short tmp[8];
#pragma unroll
    for (int j = 0; j < 4; ++j) tmp[j]     = f2bf(v0[j]);
#pragma unroll
    for (int j = 0; j < 4; ++j) tmp[4 + j] = f2bf(v1[j]);
    *(bf16x8*)dst = *(const bf16x8*)tmp;
}

// ---- staging helpers: linear LDS dest, inverse-swizzled global source ----
// A LDS row-permute: rowp -> global r = wmr*128 + mh*64 + rr, so LDS-half LO (rowp<128)
// holds both waves' mf0-3 rows and HI holds mf4-7 rows.
static __device__ __forceinline__ void stageA(const char* Ab, char* lds,
                                              int m0, int kb, int pass, int tid) {
    int off  = pass * 8192 + tid * 16;
    int rowp = off >> 7;
    int scol = (off & 127) ^ ((rowp & 7) << 4);
    int mh = rowp >> 7, wmr = (rowp >> 6) & 1, rr = rowp & 63;
    int r  = wmr * 128 + mh * 64 + rr;
    gld_lds16(Ab + (size_t)(m0 + r) * KROW + kb + scol, lds + off);
}
static __device__ __forceinline__ void stageB(const char* Wb, char* lds,
                                              int n0r, int kb, int pass, int tid) {
    int off  = pass * 8192 + tid * 16;
    int rowp = off >> 7;
    int scol = (off & 127) ^ ((rowp & 7) << 4);
    gld_lds16(Wb + (size_t)(n0r + rowp) * KROW + kb + scol, lds + off);
}

// ---- swizzled ds_read of MFMA fragments ----
static __device__ __forceinline__ bf16x8 ldA(const char* lds, int wm, int mf, int kk,
                                             int l15, int l4) {
    int rowp = (mf >> 2) * 128 + wm * 64 + (mf & 3) * 16 + l15;
    int kb   = kk * 64 + l4 * 16;
    return *(const bf16x8*)(lds + rowp * 128 + (kb ^ ((rowp & 7) << 4)));
}
static __device__ __forceinline__ bf16x8 ldB(const char* lds, int wn, int nf, int kk,
                                             int l15, int l4) {
    int rowp = wn * 64 + nf * 16 + l15;
    int kb   = kk * 64 + l4 * 16;
    return *(const bf16x8*)(lds + rowp * 128 + (kb ^ ((rowp & 7) << 4)));
}

// Raw barrier with compiler memory fence: memory ops (ds_read / gld_lds / global)
// cannot cross, but VALU/scalar scheduling and the compiler's own fine-grained
// waitcnt insertion remain free (the R3->R4 fix).
static __device__ __forceinline__ void bar() {
    asm volatile("s_barrier" ::: "memory");
}

static __device__ __forceinline__ float sigmoid_fast(float v) {
    return 1.0f / (1.0f + __expf(-v));
}
static __device__ __forceinline__ float tanh_fast(float v) {
    return 1.0f - 2.0f / (1.0f + __expf(2.0f * v));
}

// one K-tile: 4 phases
template<int CUR>
static __device__ __forceinline__ void do_tile(
        int t, const char* Ab, const char* Wb,
        char* bufA0, char* bufB0, char* bufA1, char* bufB1,
        f32x4 (&acc)[8][4], bf16x8 (&b)[4][2],
        int m0, int n0r, int tid, int wm, int wn, int l15, int l4) {
    char* cA = CUR ? bufA1 : bufA0;
    char* cB = CUR ? bufB1 : bufB0;
    char* oA = CUR ? bufA0 : bufA1;
    char* oB = CUR ? bufB0 : bufB1;
    const int  kb1 = (t + 1) * 128, kb2 = (t + 2) * 128;
    const bool g1 = (t + 1) < NT, g2 = (t + 2) < NT;
    bf16x8 a[4];

    // ---- Ph1: A(mf0-3,k0) + B(all,k0); stage B-HI of t+1 (other buf) ----
#pragma unroll
    for (int mf = 0; mf < 4; ++mf) a[mf] = ldA(cA, wm, mf, 0, l15, l4);
#pragma unroll
    for (int nf = 0; nf < 4; ++nf) b[nf][0] = ldB(cB, wn, nf, 0, l15, l4);
    if (g1) { stageB(Wb, oB, n0r, kb1, 2, tid); stageB(Wb, oB, n0r, kb1, 3, tid); }
    bar();
    __builtin_amdgcn_s_setprio(1);
#pragma unroll
    for (int mf = 0; mf < 4; ++mf)
#pragma unroll
        for (int nf = 0; nf < 4; ++nf)
            acc[mf][nf] = __builtin_amdgcn_mfma_f32_16x16x32_bf16(a[mf], b[nf][0], acc[mf][nf], 0, 0, 0);
    __builtin_amdgcn_s_setprio(0);
    bar();

    // ---- Ph2: A(mf0-3,k1) + B(all,k1); stage A-HI of t+1 (other buf) ----
#pragma unroll
    for (int mf = 0; mf < 4; ++mf) a[mf] = ldA(cA, wm, mf, 1, l15, l4);
#pragma unroll
    for (int nf = 0; nf < 4; ++nf) b[nf][1] = ldB(cB, wn, nf, 1, l15, l4);
    if (g1) { stageA(Ab, oA, m0, kb1, 2, tid); stageA(Ab, oA, m0, kb1, 3, tid); }
    bar();
    __builtin_amdgcn_s_setprio(1);
#pragma unroll
    for (int mf = 0; mf < 4; ++mf)
#pragma unroll
        for (int nf = 0; nf < 4; ++nf)
            acc[mf][nf] = __builtin_amdgcn_mfma_f32_16x16x32_bf16(a[mf], b[nf][1], acc[mf][nf], 0, 0, 0);
    __builtin_amdgcn_s_setprio(0);
    bar();

    // ---- Ph3: A(mf4-7,k0); stage A-LO of t+2 (cur buf; freed after Ph2) ----
#pragma unroll
    for (int mf = 0; mf < 4; ++mf) a[mf] = ldA(cA, wm, 4 + mf, 0, l15, l4);
    if (g2) { stageA(Ab, cA, m0, kb2, 0, tid); stageA(Ab, cA, m0, kb2, 1, tid); }
    bar();
    __builtin_amdgcn_s_setprio(1);
#pragma unroll
    for (int mf = 0; mf < 4; ++mf)
#pragma unroll
        for (int nf = 0; nf < 4; ++nf)
            acc[4 + mf][nf] = __builtin_amdgcn_mfma_f32_16x16x32_bf16(a[mf], b[nf][0], acc[4 + mf][nf], 0, 0, 0);
    __builtin_amdgcn_s_setprio(0);
    bar();

    // ---- Ph4: A(mf4-7,k1); stage B-LO of t+2 (cur buf; freed after Ph2) ----
#pragma unroll
    for (int mf = 0; mf < 4; ++mf) a[mf] = ldA(cA, wm, 4 + mf, 1, l15, l4);
    if (g2) { stageB(Wb, cB, n0r, kb2, 0, tid); stageB(Wb, cB, n0r, kb2, 1, tid); }
    bar();
    __builtin_amdgcn_s_setprio(1);
#pragma unroll
    for (int mf = 0; mf < 4; ++mf)
#pragma unroll
        for (int nf = 0; nf < 4; ++nf)
            acc[4 + mf][nf] = __builtin_amdgcn_mfma_f32_16x16x32_bf16(a[mf], b[nf][1], acc[4 + mf][nf], 0, 0, 0);
    __builtin_amdgcn_s_setprio(0);
    // tile end: counted vmcnt. Steady state: retire the 8 oldest (= all of t+1's
    // data), keep t+2's 4 in flight. Tail (no t+2 prefetch): drain fully.
    if (g2) { asm volatile("s_waitcnt vmcnt(4)" ::: "memory"); }
    else    { asm volatile("s_waitcnt vmcnt(0)" ::: "memory"); }
    bar();
}

__global__ __launch_bounds__(512, 2) void lstm_gemm(
        const unsigned short* __restrict__ Acat,
        const unsigned short* __restrict__ Wcat,
        const float* __restrict__ c,
        const float* __restrict__ bx,
        const float* __restrict__ bh,
        float* __restrict__ outH,
        float* __restrict__ outC) {
    __shared__ __align__(16) char smem[131072];
    char* bufA0 = smem;
    char* bufB0 = smem + 32768;
    char* bufA1 = smem + 65536;
    char* bufB1 = smem + 98304;

    const int tid  = threadIdx.x;
    const int lane = tid & 63;
    const int wid  = tid >> 6;
    const int wm   = wid >> 2;          // 0..1
    const int wn   = wid & 3;           // 0..3
    const int l15  = lane & 15;
    const int l4   = lane >> 4;

    const int bid = blockIdx.x;
    const int swz = (bid & 7) * 64 + (bid >> 3);   // XCD-chunked, bijective (512%8==0)
    const int mb  = swz >> 4;           // 0..31
    const int nb  = swz & 15;           // 0..15
    const int m0  = mb * 256;
    const int n0r = nb * 256;

    const char* Ab = (const char*)Acat;
    const char* Wb = (const char*)Wcat;

    f32x4 acc[8][4];
#pragma unroll
    for (int i = 0; i < 8; ++i)
#pragma unroll
        for (int j = 0; j < 4; ++j)
#pragma unroll
            for (int e = 0; e < 4; ++e) acc[i][j][e] = 0.0f;
    bf16x8 b[4][2];

    // ---- prologue: tile0 fully (8 loads) + tile1 early halves (4 loads) ----
#pragma unroll
    for (int p = 0; p < 4; ++p) stageA(Ab, bufA0, m0, 0, p, tid);
#pragma unroll
    for (int p = 0; p < 4; ++p) stageB(Wb, bufB0, n0r, 0, p, tid);
    stageA(Ab, bufA1, m0, 128, 0, tid);
    stageA(Ab, bufA1, m0, 128, 1, tid);
    stageB(Wb, bufB1, n0r, 128, 0, tid);
    stageB(Wb, bufB1, n0r, 128, 1, tid);
    asm volatile("s_waitcnt vmcnt(4)" ::: "memory");   // tile0 landed; tile1's 4 in flight
    bar();

    for (int tt = 0; tt < NT; tt += 2) {
        do_tile<0>(tt,     Ab, Wb, bufA0, bufB0, bufA1, bufB1, acc, b, m0, n0r, tid, wm, wn, l15, l4);
        do_tile<1>(tt + 1, Ab, Wb, bufA0, bufB0, bufA1, bufB1, acc, b, m0, n0r, tid, wm, wn, l15, l4);
    }

    // ---- fused LSTM epilogue, in-register: nf = gate (i,f,g,o) ----
    const int col = (nb * 4 + wn) * 16 + l15;          // output column 0..1023
    const float bi = bx[col]            + bh[col];
    const float bf = bx[1024 + col]     + bh[1024 + col];
    const float bg = bx[2048 + col]     + bh[2048 + col];
    const float bo = bx[3072 + col]     + bh[3072 + col];
#pragma unroll
    for (int mf = 0; mf < 8; ++mf) {
#pragma unroll
        for (int j = 0; j < 4; ++j) {
            const int row = m0 + wm * 128 + mf * 16 + l4 * 4 + j;
            const float iv = acc[mf][0][j] + bi;
            const float fv = acc[mf][1][j] + bf;
            const float gv = acc[mf][2][j] + bg;
            const float ov = acc[mf][3][j] + bo;
            const float ig = sigmoid_fast(iv);
            const float fg = sigmoid_fast(fv);
            const float gg = tanh_fast(gv);
            const float og = sigmoid_fast(ov);
            const float cin = c[(size_t)row * H_DIM + col];
            const float cn  = fg * cin + ig * gg;
            const float hn  = og * tanh_fast(cn);
            outH[(size_t)row * H_DIM + col] = hn;
            outC[(size_t)row * H_DIM + col] = cn;
        }
    }
}

extern "C" void kernel_launch(void* const* d_in, const int* in_sizes, int n_in,
                              void* d_out, int out_size, void* d_ws, size_t ws_size,
                              hipStream_t stream) {
    const float* x  = (const float*)d_in[0];
    const float* h  = (const float*)d_in[1];
    const float* c  = (const float*)d_in[2];
    const float* Wx = (const float*)d_in[3];
    const float* bx = (const float*)d_in[4];
    const float* Wh = (const float*)d_in[5];
    const float* bh = (const float*)d_in[6];
    float* out = (float*)d_out;

    unsigned short* Acat = (unsigned short*)d_ws;                       // 32 MB
    unsigned short* Wcat = Acat + (size_t)B_DIM * KTOT;                 // 16 MB

    hipLaunchKernelGGL(pack_all, dim3(12288), dim3(256), 0, stream, x, h, Wx, Wh, Acat, Wcat);
    hipLaunchKernelGGL(lstm_gemm, dim3(512), dim3(512), 0, stream,
                       Acat, Wcat, c, bx, bh,
                       out, out + (size_t)B_DIM * H_DIM);
}

// Round 6
// 297.926 us; speedup vs baseline: 1.0133x; 1.0133x over previous
//
#include <hip/hip_runtime.h>
#include <hip/hip_bf16.h>
#include <cstdint>
#include <cstddef>

// LSTM cell fused as one bf16 GEMM (m201-style 256^2 8-phase schedule) + in-register epilogue.
// A = [x|h] bf16 [8192][2048]. W = [Wx|Wh] bf16 [4096][2048], rows permuted
// n' = (o/16)*64 + g*16 + (o%16)  => a 64-col wave slice = 4 gates x same 16 output cols.
// GEMM: BM=BN=256, BK=64, 512 thr (8 waves 2Mx4N), per-wave 128x64, acc[8][4] f32x4.
//
// R6 change vs R5: REMOVE all "memory" clobbers from barrier/waitcnt asm.
// Theory: a memory-clobber asm may read LDS, so SIInsertWaitcnts drains vmcnt(0)
// before EVERY bar() -> the counted vmcnt(4) was dead and the prefetch pipeline
// drained once per phase (m97 drain pathology; explains R3===R5 at 38% MfmaUtil).
// m201's verified pattern is exactly: __builtin_amdgcn_s_barrier() + BARE
// asm volatile("s_waitcnt ...") with counted N. Safety without clobbers:
//  - ds_reads are compiler-visible loads -> compiler inserts data-dep lgkm waits
//    before MFMA (rule 18 n/a);
//  - gld_lds is a side-effecting intrinsic, may-aliases LDS loads -> no IR reorder;
//  - s_barrier builtin / asm volatile are MIR scheduling barriers for memory ops;
//  - write-after-read ledger: every staged region was last READ >= 2 barriers
//    earlier (audited per phase, both buffers); vmcnt FIFO retirement order =
//    program issue order of gld_lds intrinsics.
//
// Schedule per K-tile t (4 phases):
//   Ph1: ds_read A(mf0-3,k0)+B(all,k0);  stage B-HI of t+1 -> other buf
//   Ph2: ds_read A(mf0-3,k1)+B(all,k1);  stage A-HI of t+1 -> other buf
//   Ph3: ds_read A(mf4-7,k0);            stage A-LO of t+2 -> cur buf (freed after Ph2)
//   Ph4: ds_read A(mf4-7,k1);            stage B-LO of t+2 -> cur buf (freed after Ph2)
//   tile end: s_waitcnt vmcnt(4) when g2 (t+2 prefetch issued), else vmcnt(0) (tail).
//   Steady state ledger (load units, oldest first): AL(t+1)x2 BL(t+1)x2 | BH(t+1)x2
//   AH(t+1)x2 | AL(t+2)x2 BL(t+2)x2 = 12 outstanding; vmcnt(4) retires first 8 =
//   exactly tile t+1's data. Each phase: reads+stages, barrier, lgkmcnt(0),
//   setprio1, 16 MFMA, setprio0, barrier.

#define B_DIM   8192
#define IN_DIM  1024
#define H_DIM   1024
#define KTOT    2048
#define KROW    4096          // bytes per packed row
#define NT      32            // K-tiles of 64

typedef __attribute__((ext_vector_type(8))) short  bf16x8;
typedef __attribute__((ext_vector_type(4))) float  f32x4;

static __device__ __forceinline__ void gld_lds16(const void* g, void* l) {
    __builtin_amdgcn_global_load_lds(
        (const __attribute__((address_space(1))) void*)g,
        (__attribute__((address_space(3))) void*)l, 16, 0, 0);
}

static __device__ __forceinline__ unsigned short f2bf(float f) {
    union { float f; unsigned u; } v; v.f = f;
    unsigned r = v.u + 0x7fffu + ((v.u >> 16) & 1u);   // RNE
    return (unsigned short)(r >> 16);
}

// ---- fused pack: [x|h] -> Acat ; [Wx|Wh] -> Wcat (permuted rows) ----
__global__ __launch_bounds__(256) void pack_all(const float* __restrict__ x,
                                                const float* __restrict__ h,
                                                const float* __restrict__ Wx,
                                                const float* __restrict__ Wh,
                                                unsigned short* __restrict__ Acat,
                                                unsigned short* __restrict__ Wcat) {
    const int bid = blockIdx.x;
    const float* src;
    unsigned short* dst;
    int idx;
    if (bid < 8192) {                       // A part: 8192*2048/8 chunks
        idx = bid * 256 + threadIdx.x;
        int row = idx >> 8;
        int k0  = (idx & 255) * 8;
        src = (k0 < IN_DIM) ? (x + (size_t)row * IN_DIM + k0)
                            : (h + (size_t)row * H_DIM + (k0 - IN_DIM));
        dst = Acat + (size_t)idx * 8;
    } else {                                // W part: 4096*2048/8 chunks
        idx = (bid - 8192) * 256 + threadIdx.x;
        int n  = idx >> 8;                  // permuted row n'
        int k0 = (idx & 255) * 8;
        int ob64 = n >> 6, g = (n >> 4) & 3, ol = n & 15;
        int o = ob64 * 16 + ol;
        src = (k0 < IN_DIM)
            ? (Wx + (size_t)(g * H_DIM + o) * IN_DIM + k0)
            : (Wh + (size_t)(g * H_DIM + o) * H_DIM + (k0 - IN_DIM));
        dst = Wcat + (size_t)idx * 8;
    }
    f32x4 v0 = *(const f32x4*)src;
    f32x4 v1 = *(const f32x4*)(src + 4);
    unsigned short tmp[8];
#pragma unroll
    for (int j = 0; j < 4; ++j) tmp[j]     = f2bf(v0[j]);
#pragma unroll
    for (int j = 0; j < 4; ++j) tmp[4 + j] = f2bf(v1[j]);
    *(bf16x8*)dst = *(const bf16x8*)tmp;
}

// ---- staging helpers: linear LDS dest, inverse-swizzled global source ----
// A LDS row-permute: rowp -> global r = wmr*128 + mh*64 + rr, so LDS-half LO (rowp<128)
// holds both waves' mf0-3 rows and HI holds mf4-7 rows.
static __device__ __forceinline__ void stageA(const char* Ab, char* lds,
                                              int m0, int kb, int pass, int tid) {
    int off  = pass * 8192 + tid * 16;
    int rowp = off >> 7;
    int scol = (off & 127) ^ ((rowp & 7) << 4);
    int mh = rowp >> 7, wmr = (rowp >> 6) & 1, rr = rowp & 63;
    int r  = wmr * 128 + mh * 64 + rr;
    gld_lds16(Ab + (size_t)(m0 + r) * KROW + kb + scol, lds + off);
}
static __device__ __forceinline__ void stageB(const char* Wb, char* lds,
                                              int n0r, int kb, int pass, int tid) {
    int off  = pass * 8192 + tid * 16;
    int rowp = off >> 7;
    int scol = (off & 127) ^ ((rowp & 7) << 4);
    gld_lds16(Wb + (size_t)(n0r + rowp) * KROW + kb + scol, lds + off);
}

// ---- swizzled ds_read of MFMA fragments ----
static __device__ __forceinline__ bf16x8 ldA(const char* lds, int wm, int mf, int kk,
                                             int l15, int l4) {
    int rowp = (mf >> 2) * 128 + wm * 64 + (mf & 3) * 16 + l15;
    int kb   = kk * 64 + l4 * 16;
    return *(const bf16x8*)(lds + rowp * 128 + (kb ^ ((rowp & 7) << 4)));
}
static __device__ __forceinline__ bf16x8 ldB(const char* lds, int wn, int nf, int kk,
                                             int l15, int l4) {
    int rowp = wn * 64 + nf * 16 + l15;
    int kb   = kk * 64 + l4 * 16;
    return *(const bf16x8*)(lds + rowp * 128 + (kb ^ ((rowp & 7) << 4)));
}

// m201 discipline: raw builtin barrier (no memory semantics, no forced drains),
// bare counted waitcnts. No "memory" clobbers anywhere in the hot loop.
static __device__ __forceinline__ void bar() {
    __builtin_amdgcn_s_barrier();
}
static __device__ __forceinline__ void wait_lgkm0() {
    asm volatile("s_waitcnt lgkmcnt(0)");
}

static __device__ __forceinline__ float sigmoid_fast(float v) {
    return 1.0f / (1.0f + __expf(-v));
}
static __device__ __forceinline__ float tanh_fast(float v) {
    return 1.0f - 2.0f / (1.0f + __expf(2.0f * v));
}

// one K-tile: 4 phases
template<int CUR>
static __device__ __forceinline__ void do_tile(
        int t, const char* Ab, const char* Wb,
        char* bufA0, char* bufB0, char* bufA1, char* bufB1,
        f32x4 (&acc)[8][4], bf16x8 (&b)[4][2],
        int m0, int n0r, int tid, int wm, int wn, int l15, int l4) {
    char* cA = CUR ? bufA1 : bufA0;
    char* cB = CUR ? bufB1 : bufB0;
    char* oA = CUR ? bufA0 : bufA1;
    char* oB = CUR ? bufB0 : bufB1;
    const int  kb1 = (t + 1) * 128, kb2 = (t + 2) * 128;
    const bool g1 = (t + 1) < NT, g2 = (t + 2) < NT;
    bf16x8 a[4];

    // ---- Ph1: A(mf0-3,k0) + B(all,k0); stage B-HI of t+1 (other buf) ----
#pragma unroll
    for (int mf = 0; mf < 4; ++mf) a[mf] = ldA(cA, wm, mf, 0, l15, l4);
#pragma unroll
    for (int nf = 0; nf < 4; ++nf) b[nf][0] = ldB(cB, wn, nf, 0, l15, l4);
    if (g1) { stageB(Wb, oB, n0r, kb1, 2, tid); stageB(Wb, oB, n0r, kb1, 3, tid); }
    bar();
    wait_lgkm0();
    __builtin_amdgcn_s_setprio(1);
#pragma unroll
    for (int mf = 0; mf < 4; ++mf)
#pragma unroll
        for (int nf = 0; nf < 4; ++nf)
            acc[mf][nf] = __builtin_amdgcn_mfma_f32_16x16x32_bf16(a[mf], b[nf][0], acc[mf][nf], 0, 0, 0);
    __builtin_amdgcn_s_setprio(0);
    bar();

    // ---- Ph2: A(mf0-3,k1) + B(all,k1); stage A-HI of t+1 (other buf) ----
#pragma unroll
    for (int mf = 0; mf < 4; ++mf) a[mf] = ldA(cA, wm, mf, 1, l15, l4);
#pragma unroll
    for (int nf = 0; nf < 4; ++nf) b[nf][1] = ldB(cB, wn, nf, 1, l15, l4);
    if (g1) { stageA(Ab, oA, m0, kb1, 2, tid); stageA(Ab, oA, m0, kb1, 3, tid); }
    bar();
    wait_lgkm0();
    __builtin_amdgcn_s_setprio(1);
#pragma unroll
    for (int mf = 0; mf < 4; ++mf)
#pragma unroll
        for (int nf = 0; nf < 4; ++nf)
            acc[mf][nf] = __builtin_amdgcn_mfma_f32_16x16x32_bf16(a[mf], b[nf][1], acc[mf][nf], 0, 0, 0);
    __builtin_amdgcn_s_setprio(0);
    bar();

    // ---- Ph3: A(mf4-7,k0); stage A-LO of t+2 (cur buf; freed after Ph2) ----
#pragma unroll
    for (int mf = 0; mf < 4; ++mf) a[mf] = ldA(cA, wm, 4 + mf, 0, l15, l4);
    if (g2) { stageA(Ab, cA, m0, kb2, 0, tid); stageA(Ab, cA, m0, kb2, 1, tid); }
    bar();
    wait_lgkm0();
    __builtin_amdgcn_s_setprio(1);
#pragma unroll
    for (int mf = 0; mf < 4; ++mf)
#pragma unroll
        for (int nf = 0; nf < 4; ++nf)
            acc[4 + mf][nf] = __builtin_amdgcn_mfma_f32_16x16x32_bf16(a[mf], b[nf][0], acc[4 + mf][nf], 0, 0, 0);
    __builtin_amdgcn_s_setprio(0);
    bar();

    // ---- Ph4: A(mf4-7,k1); stage B-LO of t+2 (cur buf; freed after Ph2) ----
#pragma unroll
    for (int mf = 0; mf < 4; ++mf) a[mf] = ldA(cA, wm, 4 + mf, 1, l15, l4);
    if (g2) { stageB(Wb, cB, n0r, kb2, 0, tid); stageB(Wb, cB, n0r, kb2, 1, tid); }
    bar();
    wait_lgkm0();
    __builtin_amdgcn_s_setprio(1);
#pragma unroll
    for (int mf = 0; mf < 4; ++mf)
#pragma unroll
        for (int nf = 0; nf < 4; ++nf)
            acc[4 + mf][nf] = __builtin_amdgcn_mfma_f32_16x16x32_bf16(a[mf], b[nf][1], acc[4 + mf][nf], 0, 0, 0);
    __builtin_amdgcn_s_setprio(0);
    // tile end: counted vmcnt. Steady state: retire the 8 oldest (= all of t+1's
    // data), keep t+2's 4 in flight. Tail (no t+2 prefetch): drain fully.
    if (g2) { asm volatile("s_waitcnt vmcnt(4)"); }
    else    { asm volatile("s_waitcnt vmcnt(0)"); }
    bar();
}

__global__ __launch_bounds__(512, 2) void lstm_gemm(
        const unsigned short* __restrict__ Acat,
        const unsigned short* __restrict__ Wcat,
        const float* __restrict__ c,
        const float* __restrict__ bx,
        const float* __restrict__ bh,
        float* __restrict__ outH,
        float* __restrict__ outC) {
    __shared__ __align__(16) char smem[131072];
    char* bufA0 = smem;
    char* bufB0 = smem + 32768;
    char* bufA1 = smem + 65536;
    char* bufB1 = smem + 98304;

    const int tid  = threadIdx.x;
    const int lane = tid & 63;
    const int wid  = tid >> 6;
    const int wm   = wid >> 2;          // 0..1
    const int wn   = wid & 3;           // 0..3
    const int l15  = lane & 15;
    const int l4   = lane >> 4;

    const int bid = blockIdx.x;
    const int swz = (bid & 7) * 64 + (bid >> 3);   // XCD-chunked, bijective (512%8==0)
    const int mb  = swz >> 4;           // 0..31
    const int nb  = swz & 15;           // 0..15
    const int m0  = mb * 256;
    const int n0r = nb * 256;

    const char* Ab = (const char*)Acat;
    const char* Wb = (const char*)Wcat;

    f32x4 acc[8][4];
#pragma unroll
    for (int i = 0; i < 8; ++i)
#pragma unroll
        for (int j = 0; j < 4; ++j)
#pragma unroll
            for (int e = 0; e < 4; ++e) acc[i][j][e] = 0.0f;
    bf16x8 b[4][2];

    // ---- prologue: tile0 fully (8 loads) + tile1 early halves (4 loads) ----
#pragma unroll
    for (int p = 0; p < 4; ++p) stageA(Ab, bufA0, m0, 0, p, tid);
#pragma unroll
    for (int p = 0; p < 4; ++p) stageB(Wb, bufB0, n0r, 0, p, tid);
    stageA(Ab, bufA1, m0, 128, 0, tid);
    stageA(Ab, bufA1, m0, 128, 1, tid);
    stageB(Wb, bufB1, n0r, 128, 0, tid);
    stageB(Wb, bufB1, n0r, 128, 1, tid);
    asm volatile("s_waitcnt vmcnt(4)");   // tile0 landed; tile1's 4 in flight
    bar();

    for (int tt = 0; tt < NT; tt += 2) {
        do_tile<0>(tt,     Ab, Wb, bufA0, bufB0, bufA1, bufB1, acc, b, m0, n0r, tid, wm, wn, l15, l4);
        do_tile<1>(tt + 1, Ab, Wb, bufA0, bufB0, bufA1, bufB1, acc, b, m0, n0r, tid, wm, wn, l15, l4);
    }

    // ---- fused LSTM epilogue, in-register: nf = gate (i,f,g,o) ----
    const int col = (nb * 4 + wn) * 16 + l15;          // output column 0..1023
    const float bi = bx[col]            + bh[col];
    const float bf = bx[1024 + col]     + bh[1024 + col];
    const float bg = bx[2048 + col]     + bh[2048 + col];
    const float bo = bx[3072 + col]     + bh[3072 + col];
#pragma unroll
    for (int mf = 0; mf < 8; ++mf) {
#pragma unroll
        for (int j = 0; j < 4; ++j) {
            const int row = m0 + wm * 128 + mf * 16 + l4 * 4 + j;
            const float iv = acc[mf][0][j] + bi;
            const float fv = acc[mf][1][j] + bf;
            const float gv = acc[mf][2][j] + bg;
            const float ov = acc[mf][3][j] + bo;
            const float ig = sigmoid_fast(iv);
            const float fg = sigmoid_fast(fv);
            const float gg = tanh_fast(gv);
            const float og = sigmoid_fast(ov);
            const float cin = c[(size_t)row * H_DIM + col];
            const float cn  = fg * cin + ig * gg;
            const float hn  = og * tanh_fast(cn);
            outH[(size_t)row * H_DIM + col] = hn;
            outC[(size_t)row * H_DIM + col] = cn;
        }
    }
}

extern "C" void kernel_launch(void* const* d_in, const int* in_sizes, int n_in,
                              void* d_out, int out_size, void* d_ws, size_t ws_size,
                              hipStream_t stream) {
    const float* x  = (const float*)d_in[0];
    const float* h  = (const float*)d_in[1];
    const float* c  = (const float*)d_in[2];
    const float* Wx = (const float*)d_in[3];
    const float* bx = (const float*)d_in[4];
    const float* Wh = (const float*)d_in[5];
    const float* bh = (const float*)d_in[6];
    float* out = (float*)d_out;

    unsigned short* Acat = (unsigned short*)d_ws;                       // 32 MB
    unsigned short* Wcat = Acat + (size_t)B_DIM * KTOT;                 // 16 MB

    hipLaunchKernelGGL(pack_all, dim3(12288), dim3(256), 0, stream, x, h, Wx, Wh, Acat, Wcat);
    hipLaunchKernelGGL(lstm_gemm, dim3(512), dim3(512), 0, stream,
                       Acat, Wcat, c, bx, bh,
                       out, out + (size_t)B_DIM * H_DIM);
}